// Round 2
// baseline (32029.932 us; speedup 1.0000x reference)
//
#include <hip/hip_runtime.h>
#include <cfloat>
#include <cmath>

#define Bn 128
#define Tn 512
#define En 256
#define Hn 512
#define NTAGS 32
#define HSTR 132            // padded b-stride for h rows / staged chunks
#define CHUNKF (64 * HSTR)  // floats per staged 64-k chunk

// ws float offsets
#define OFF_HF 0                          // [2][512][132] fwd h (k-major, padded)
#define OFF_HB (2 * Tn * HSTR)            // 135168
#define OFF_CF (2 * (2 * Tn * HSTR))      // 270336: [512][128] fwd c
#define OFF_CB (OFF_CF + Hn * Bn)         // 335872
#define OFF_EF (OFF_CB + Hn * Bn)         // 401408: [512][32][128] emissions fwd
#define OFF_EB (OFF_EF + Tn * NTAGS * Bn) // 2498560
// end: 4595712 floats = 17.53 MB

__device__ __forceinline__ void gll16(const float* g, float* l) {
  __builtin_amdgcn_global_load_lds(
      (const __attribute__((address_space(1))) void*)g,
      (__attribute__((address_space(3))) void*)l, 16, 0, 0);
}

__global__ __launch_bounds__(256, 1) void lstm_step_k(
    const float* __restrict__ X, const float* __restrict__ masks,
    const float* __restrict__ Wih_f, const float* __restrict__ Whh_f, const float* __restrict__ bias_f,
    const float* __restrict__ Wih_b, const float* __restrict__ Whh_b, const float* __restrict__ bias_b,
    const float* __restrict__ Wout, float* __restrict__ ws, int s)
{
  __shared__ __align__(16) float WT[768 * 16];      // 48 KB, [k][c]
  __shared__ __align__(16) float HX[2 * CHUNKF];    // 66 KB, two staged chunks [k][b(132)]
  __shared__ __align__(16) float GL[128 * 17];      // 8.5 KB gates [b][c], pad 17

  const int tid = threadIdx.x;
  const int blk = blockIdx.x;

  const int dir = blk >> 7;
  const int bbk = blk & 127;
  const int t = dir ? (Tn - 1 - s) : s;
  const float* Wih  = dir ? Wih_b  : Wih_f;
  const float* Whh  = dir ? Whh_b  : Whh_f;
  const float* bias = dir ? bias_b : bias_f;
  float* hbuf = ws + (dir ? OFF_HB : OFF_HF);
  float* cbuf = ws + (dir ? OFF_CB : OFF_CF);
  const int rbuf = (s + 1) & 1;
  const int wbuf = s & 1;
  const float* hprev = hbuf + rbuf * (Hn * HSTR);
  float*       hnext = hbuf + wbuf * (Hn * HSTR);
  const int hidx0 = bbk * 4;

  // thread decomposition: bt (16 batch tiles of 8) x ct (2 col tiles of 8) x sseg (8-way K interleave)
  const int bt   = tid & 15;
  const int ct   = (tid >> 4) & 1;
  const int sseg = tid >> 5;
  const int b0   = bt * 8;
  const int c0   = ct * 8;

  // ---- prologue: issue chunk-0 (h) loads, then stage W ----
  {
    #pragma unroll
    for (int r = 0; r < 8; ++r) {
      const int item = r * 256 + tid;           // float4 index within chunk
      gll16(hprev + item * 4, HX + item * 4);
    }
    if (tid < 64) {                              // tail: 2112 - 2048 items
      const int item = 2048 + tid;
      gll16(hprev + item * 4, HX + item * 4);
    }
  }
  {
    const int lc  = tid & 15;                    // local col 0..15
    const int row = (lc >> 2) * Hn + hidx0 + (lc & 3);
    #pragma unroll
    for (int r = 0; r < 12; ++r) {
      const int k4 = r * 16 + (tid >> 4);        // 0..191
      const int k  = k4 * 4;
      float4 w4;
      if (k < Hn) w4 = *(const float4*)&Whh[(size_t)row * Hn + k];
      else        w4 = *(const float4*)&Wih[(size_t)row * En + (k - Hn)];
      WT[(k + 0) * 16 + lc] = w4.x; WT[(k + 1) * 16 + lc] = w4.y;
      WT[(k + 2) * 16 + lc] = w4.z; WT[(k + 3) * 16 + lc] = w4.w;
    }
  }
  __syncthreads();

  float acc[8][8];
  #pragma unroll
  for (int m = 0; m < 8; ++m)
    #pragma unroll
    for (int n = 0; n < 8; ++n) acc[m][n] = 0.f;

  float4 xr[8];

  // ---- main loop: 12 chunks (0..7 = h from hprev, 8..11 = x from X) ----
  #pragma unroll
  for (int c = 0; c < 12; ++c) {
    const int nxt = c + 1;
    // stage next chunk
    if (nxt < 8) {
      float* dst = HX + (nxt & 1) * CHUNKF;
      const float* src = hprev + nxt * CHUNKF;
      #pragma unroll
      for (int r = 0; r < 8; ++r) {
        const int item = r * 256 + tid;
        gll16(src + item * 4, dst + item * 4);
      }
      if (tid < 64) {
        const int item = 2048 + tid;
        gll16(src + item * 4, dst + item * 4);
      }
    } else if (nxt < 12) {
      const int e0 = (nxt - 8) * 64;
      const int bq = tid & 127;
      #pragma unroll
      for (int r = 0; r < 8; ++r) {
        const int k4 = 2 * r + (tid >> 7);       // 0..15
        xr[r] = *(const float4*)&X[(size_t)bq * (Tn * En) + (size_t)t * En + e0 + k4 * 4];
      }
    }
    // compute current chunk
    {
      const float* HXc = HX + (c & 1) * CHUNKF;
      #pragma unroll
      for (int i = 0; i < 8; ++i) {
        const int kl = i * 8 + sseg;
        const int kg = c * 64 + kl;
        float4 ha = *(const float4*)&HXc[kl * HSTR + b0];
        float4 hb = *(const float4*)&HXc[kl * HSTR + b0 + 4];
        float4 wa = *(const float4*)&WT[kg * 16 + c0];
        float4 wb = *(const float4*)&WT[kg * 16 + c0 + 4];
        const float hv[8] = {ha.x, ha.y, ha.z, ha.w, hb.x, hb.y, hb.z, hb.w};
        const float wv[8] = {wa.x, wa.y, wa.z, wa.w, wb.x, wb.y, wb.z, wb.w};
        #pragma unroll
        for (int m = 0; m < 8; ++m)
          #pragma unroll
          for (int n = 0; n < 8; ++n)
            acc[m][n] += hv[m] * wv[n];
      }
    }
    // write x regs into next buffer (safe: that buffer's readers finished a barrier ago)
    if (nxt >= 8 && nxt < 12) {
      float* dst = HX + (nxt & 1) * CHUNKF;
      const int bq = tid & 127;
      #pragma unroll
      for (int r = 0; r < 8; ++r) {
        const int k4 = 2 * r + (tid >> 7);
        dst[(k4 * 4 + 0) * HSTR + bq] = xr[r].x;
        dst[(k4 * 4 + 1) * HSTR + bq] = xr[r].y;
        dst[(k4 * 4 + 2) * HSTR + bq] = xr[r].z;
        dst[(k4 * 4 + 3) * HSTR + bq] = xr[r].w;
      }
    }
    __syncthreads();
  }

  // ---- reduce 8 K-segments via LDS (two passes, tiles stride 132 in HX area) ----
  float* RED = HX;
  if (sseg < 4) {
    const int tb = (sseg * 16 + bt) * HSTR + ct * 8;
    #pragma unroll
    for (int mb = 0; mb < 8; ++mb) {
      *(float4*)&RED[tb + mb * 16]     = make_float4(acc[mb][0], acc[mb][1], acc[mb][2], acc[mb][3]);
      *(float4*)&RED[tb + mb * 16 + 4] = make_float4(acc[mb][4], acc[mb][5], acc[mb][6], acc[mb][7]);
    }
  }
  __syncthreads();
  float psum[8] = {0.f, 0.f, 0.f, 0.f, 0.f, 0.f, 0.f, 0.f};
  const int bq_r = tid >> 1;
  const int cb_r = (tid & 1) * 8;
  const int bt_r = bq_r >> 3;
  const int mb_r = bq_r & 7;
  #pragma unroll
  for (int sp = 0; sp < 4; ++sp) {
    const int idx = (sp * 16 + bt_r) * HSTR + mb_r * 16 + cb_r;
    float4 a0 = *(const float4*)&RED[idx];
    float4 a1 = *(const float4*)&RED[idx + 4];
    psum[0] += a0.x; psum[1] += a0.y; psum[2] += a0.z; psum[3] += a0.w;
    psum[4] += a1.x; psum[5] += a1.y; psum[6] += a1.z; psum[7] += a1.w;
  }
  __syncthreads();
  if (sseg >= 4) {
    const int tb = ((sseg - 4) * 16 + bt) * HSTR + ct * 8;
    #pragma unroll
    for (int mb = 0; mb < 8; ++mb) {
      *(float4*)&RED[tb + mb * 16]     = make_float4(acc[mb][0], acc[mb][1], acc[mb][2], acc[mb][3]);
      *(float4*)&RED[tb + mb * 16 + 4] = make_float4(acc[mb][4], acc[mb][5], acc[mb][6], acc[mb][7]);
    }
  }
  __syncthreads();
  #pragma unroll
  for (int sp = 0; sp < 4; ++sp) {
    const int idx = (sp * 16 + bt_r) * HSTR + mb_r * 16 + cb_r;
    float4 a0 = *(const float4*)&RED[idx];
    float4 a1 = *(const float4*)&RED[idx + 4];
    psum[0] += a0.x; psum[1] += a0.y; psum[2] += a0.z; psum[3] += a0.w;
    psum[4] += a1.x; psum[5] += a1.y; psum[6] += a1.z; psum[7] += a1.w;
  }
  #pragma unroll
  for (int j = 0; j < 8; ++j) GL[bq_r * 17 + cb_r + j] = psum[j];
  __syncthreads();

  // ---- LSTM pointwise update: 512 (b, hh) items over 256 threads ----
  #pragma unroll
  for (int r = 0; r < 2; ++r) {
    const int item = tid + r * 256;
    const int b  = item & 127;
    const int hh = item >> 7;                    // 0..3
    const int hidx = hidx0 + hh;
    const float gi = GL[b * 17 + hh]      + bias[hidx];
    const float gf = GL[b * 17 + 4 + hh]  + bias[Hn + hidx];
    const float gc = GL[b * 17 + 8 + hh]  + bias[2 * Hn + hidx];
    const float go = GL[b * 17 + 12 + hh] + bias[3 * Hn + hidx];
    const float iv = 1.f / (1.f + expf(-gi));
    const float fv = 1.f / (1.f + expf(-gf));
    const float gv = tanhf(gc);
    const float ov = 1.f / (1.f + expf(-go));
    const float cold = cbuf[hidx * Bn + b];
    const float cnew = fv * cold + iv * gv;
    const float hold = hprev[hidx * HSTR + b];
    const float hnew = ov * tanhf(cnew);
    const float m = masks[(size_t)b * Tn + t];
    hnext[hidx * HSTR + b] = (m > 0.f) ? hnew : hold;
    cbuf[hidx * Bn + b]    = (m > 0.f) ? cnew : cold;
  }

  // ---- emission tail: blocks 0..63 compute E[tprev][tag][:] for (dir_e, tag) ----
  if (blk < 64 && s > 0) {
    __syncthreads();                             // GL reads done; reuse as scratch
    float* RS = GL;
    const int dir_e = blk >> 5;
    const int tag   = blk & 31;
    const float* hsrc = ws + (dir_e ? OFF_HB : OFF_HF) + rbuf * (Hn * HSTR);
    const int tprev = dir_e ? (Tn - s) : (s - 1);
    const float* wrow = Wout + (size_t)tag * (2 * Hn) + dir_e * Hn;
    float* Edst = ws + (dir_e ? OFF_EB : OFF_EF);
    const int b  = tid & 127;
    const int kh = tid >> 7;
    float a = 0.f;
    #pragma unroll 4
    for (int k = kh * 256; k < kh * 256 + 256; ++k)
      a += hsrc[k * HSTR + b] * wrow[k];
    RS[kh * 128 + b] = a;
    __syncthreads();
    if (tid < 128)
      Edst[(size_t)tprev * (NTAGS * Bn) + tag * Bn + tid] = RS[tid] + RS[128 + tid];
  }
}

__global__ __launch_bounds__(512) void emis_final_k(const float* __restrict__ Wout,
                                                    float* __restrict__ ws)
{
  __shared__ float rs_[4][128];
  const int tid = threadIdx.x;
  const int dir = blockIdx.x >> 5;
  const int tag = blockIdx.x & 31;
  const float* hsrc = ws + (dir ? OFF_HB : OFF_HF) + 1 * (Hn * HSTR);
  const int tprev = dir ? 0 : (Tn - 1);
  const float* wrow = Wout + (size_t)tag * (2 * Hn) + dir * Hn;
  float* Edst = ws + (dir ? OFF_EB : OFF_EF);
  const int b  = tid & 127;
  const int kh = tid >> 7;
  float a = 0.f;
  #pragma unroll 4
  for (int k = kh * 128; k < kh * 128 + 128; ++k)
    a += hsrc[k * HSTR + b] * wrow[k];
  rs_[kh][b] = a;
  __syncthreads();
  if (tid < 128) {
    const float v = rs_[0][tid] + rs_[1][tid] + rs_[2][tid] + rs_[3][tid];
    Edst[(size_t)tprev * (NTAGS * Bn) + tag * Bn + tid] = v;
  }
}

__global__ __launch_bounds__(64) void viterbi_k(
    const float* __restrict__ Ef, const float* __restrict__ Eb,
    const float* __restrict__ bout, const float* __restrict__ trans,
    const float* __restrict__ masks, float* __restrict__ out)
{
  const int b = blockIdx.x;
  const int l = threadIdx.x;
  __shared__ float tr[32][32];
  __shared__ float al[32];
  __shared__ float msk[512];
  __shared__ unsigned char bp[512][32];
  __shared__ int tseq[512];

  for (int i = l; i < 1024; i += 64) tr[i >> 5][i & 31] = trans[i];
  for (int i = l; i < 512; i += 64) msk[i] = masks[(size_t)b * 512 + i];
  __syncthreads();

  const int j  = l & 31;
  const int hi = l >> 5;
  if (l < 32)
    al[j] = Ef[(size_t)j * Bn + b] + Eb[(size_t)j * Bn + b] + bout[j] + tr[30][j];
  __syncthreads();

  for (int t = 1; t < 512; ++t) {
    float pmax = -FLT_MAX; int pidx = 0;
    #pragma unroll
    for (int ii = 0; ii < 16; ++ii) {
      const int i = hi * 16 + ii;
      const float sc = al[i] + tr[i][j];
      if (sc > pmax) { pmax = sc; pidx = i; }   // strict > => first occurrence
    }
    const float omax = __shfl_down(pmax, 32);
    const int   oidx = __shfl_down(pidx, 32);
    if (l < 32) {
      if (omax > pmax) { pmax = omax; pidx = oidx; } // high half only on strict >
      bp[t][j] = (unsigned char)pidx;
      const float e = Ef[(size_t)t * (NTAGS * Bn) + j * Bn + b]
                    + Eb[(size_t)t * (NTAGS * Bn) + j * Bn + b] + bout[j];
      const float na = pmax + e;
      if (msk[t] > 0.f) al[j] = na;
    }
    __syncthreads();
  }

  float fv; int fidx;
  if (l < 32) { fv = al[l] + tr[l][31]; fidx = l; }
  else        { fv = -FLT_MAX; fidx = 1 << 30; }
  #pragma unroll
  for (int off = 16; off >= 1; off >>= 1) {
    const float v2 = __shfl_xor(fv, off);
    const int   i2 = __shfl_xor(fidx, off);
    if (v2 > fv || (v2 == fv && i2 < fidx)) { fv = v2; fidx = i2; }
  }
  if (l == 0) {
    out[b] = fv;
    int cur = fidx;
    tseq[511] = cur;
    for (int t = 511; t >= 1; --t) {
      const int prev = (msk[t] > 0.f) ? (int)bp[t][cur] : cur;
      tseq[t - 1] = prev;
      cur = prev;
    }
  }
  __syncthreads();
  for (int t = l; t < 512; t += 64) {
    const float tv = (msk[t] > 0.f) ? (float)tseq[t] : -1.0f;
    out[Bn + (size_t)b * 512 + t] = tv;
  }
}

extern "C" void kernel_launch(void* const* d_in, const int* in_sizes, int n_in,
                              void* d_out, int out_size, void* d_ws, size_t ws_size,
                              hipStream_t stream) {
  const float* X      = (const float*)d_in[0];
  const float* masks  = (const float*)d_in[1];
  const float* Wih_f  = (const float*)d_in[3];
  const float* Whh_f  = (const float*)d_in[4];
  const float* bf     = (const float*)d_in[5];
  const float* Wih_b  = (const float*)d_in[6];
  const float* Whh_b  = (const float*)d_in[7];
  const float* bb     = (const float*)d_in[8];
  const float* Wout   = (const float*)d_in[9];
  const float* bout   = (const float*)d_in[10];
  const float* trans  = (const float*)d_in[11];
  float* ws  = (float*)d_ws;
  float* out = (float*)d_out;

  // zero h/c state region (graph replays re-run this)
  hipMemsetAsync(d_ws, 0, (size_t)OFF_EF * sizeof(float), stream);

  for (int s = 0; s < Tn; ++s)
    lstm_step_k<<<256, 256, 0, stream>>>(X, masks, Wih_f, Whh_f, bf,
                                         Wih_b, Whh_b, bb, Wout, ws, s);
  emis_final_k<<<64, 512, 0, stream>>>(Wout, ws);
  viterbi_k<<<128, 64, 0, stream>>>(ws + OFF_EF, ws + OFF_EB, bout, trans, masks, out);
}

// Round 3
// 18480.095 us; speedup vs baseline: 1.7332x; 1.7332x over previous
//
#include <hip/hip_runtime.h>
#include <cfloat>
#include <cmath>

#define Bn 128
#define Tn 512
#define En 256
#define Hn 512
#define NTAGS 32
#define CHK 128                  // k-rows per staged chunk
#define NCHK 6                   // 4 h-chunks (512 k) + 2 x-chunks (256 k)

// ws float offsets (h stored transposed [k][b], NO padding - gll16 linear dest)
#define OFF_HF 0                          // [2][512][128]
#define OFF_HB 131072
#define OFF_CF 262144                     // [512][128]
#define OFF_CB 327680
#define OFF_EF 393216                     // [512][32][128]
#define OFF_EB 2490368
// end 4587520 floats = 17.5 MB (same footprint as round 1)

__device__ __forceinline__ void gll16(const float* g, float* l) {
  __builtin_amdgcn_global_load_lds(
      (const __attribute__((address_space(1))) void*)g,
      (__attribute__((address_space(3))) void*)l, 16, 0, 0);
}

__global__ __launch_bounds__(512, 2) void lstm_step_k(
    const float* __restrict__ X, const float* __restrict__ masks,
    const float* __restrict__ Wih_f, const float* __restrict__ Whh_f, const float* __restrict__ bias_f,
    const float* __restrict__ Wih_b, const float* __restrict__ Whh_b, const float* __restrict__ bias_b,
    const float* __restrict__ Wout, float* __restrict__ ws, int s)
{
  __shared__ __align__(16) float HX[2][CHK * Bn];  // 2 x 64 KB A-chunks [k][b]
  __shared__ __align__(16) float GL[Bn * 17];      // gates [b][c], pad 17

  const int tid  = threadIdx.x;
  const int blk  = blockIdx.x;
  const int lane = tid & 63;
  const int wid  = __builtin_amdgcn_readfirstlane(tid >> 6);  // 0..7, uniform
  const int cg   = wid & 1;   // c-half: cols [cg*8, cg*8+8)
  const int kt   = wid >> 1;  // k-quarter within chunk: [kt*32, kt*32+32)

  const int dir = blk >> 7;
  const int bbk = blk & 127;
  const int t = dir ? (Tn - 1 - s) : s;
  const float* Wih  = dir ? Wih_b  : Wih_f;
  const float* Whh  = dir ? Whh_b  : Whh_f;
  const float* bias = dir ? bias_b : bias_f;
  float* hbuf = ws + (dir ? OFF_HB : OFF_HF);
  float* cbuf = ws + (dir ? OFF_CB : OFF_CF);
  const int rbuf = (s + 1) & 1;
  const int wbuf = s & 1;
  const float* hprev = hbuf + rbuf * (Hn * Bn);
  float*       hnext = hbuf + wbuf * (Hn * Bn);
  const int hidx0 = bbk * 4;

  // ---- prologue: stage chunk 0 (h rows 0..127) ----
  #pragma unroll
  for (int r = 0; r < 8; ++r) {
    const int item = r * 512 + tid;                // float4 index, 4096 total
    gll16(hprev + item * 4, &HX[0][item * 4]);
  }
  __syncthreads();

  float acc[2][8];
  #pragma unroll
  for (int m = 0; m < 2; ++m)
    #pragma unroll
    for (int n = 0; n < 8; ++n) acc[m][n] = 0.f;
  float4 xr[8];

  // ---- main loop: 6 chunks, rolled (code size!) ----
  #pragma unroll 1
  for (int c = 0; c < NCHK; ++c) {
    const int nxt = c + 1;
    if (nxt < 4) {
      // stage next h-chunk via global_load_lds (fire and forget)
      const float* src = hprev + nxt * (CHK * Bn);
      float* dst = &HX[nxt & 1][0];
      #pragma unroll
      for (int r = 0; r < 8; ++r) {
        const int item = r * 512 + tid;
        gll16(src + item * 4, dst + item * 4);
      }
    } else if (nxt < NCHK) {
      // next is x-chunk: load X slice into regs (transpose happens at ds_write)
      const int e0 = (nxt - 4) * CHK;
      const int bq = tid & 127;
      const int eg = tid >> 7;                     // 0..3
      #pragma unroll
      for (int r = 0; r < 8; ++r) {
        const int e = e0 + eg * 32 + r * 4;
        xr[r] = *(const float4*)&X[(size_t)bq * (Tn * En) + (size_t)t * En + e];
      }
    }

    // ---- compute chunk c: 32 k per wave, A from LDS (b64), W via uniform s_load ----
    {
      const float* HXc = &HX[c & 1][0];
      const float* wb[8];
      #pragma unroll
      for (int n = 0; n < 8; ++n) {
        const int lc  = cg * 8 + n;                     // local col 0..15
        const int row = (lc >> 2) * Hn + hidx0 + (lc & 3);
        wb[n] = (c < 4) ? (Whh + (size_t)row * Hn + c * CHK + kt * 32)
                        : (Wih + (size_t)row * En + (c - 4) * CHK + kt * 32);
      }
      #pragma unroll
      for (int p = 0; p < 8; ++p) {                     // 4 k per phase
        float4 wv[8];
        #pragma unroll
        for (int n = 0; n < 8; ++n) wv[n] = *(const float4*)(wb[n] + p * 4);
        const int kb = (kt * 32 + p * 4) * Bn + lane * 2;
        const float2 a0 = *(const float2*)&HXc[kb];
        const float2 a1 = *(const float2*)&HXc[kb + Bn];
        const float2 a2 = *(const float2*)&HXc[kb + 2 * Bn];
        const float2 a3 = *(const float2*)&HXc[kb + 3 * Bn];
        #pragma unroll
        for (int n = 0; n < 8; ++n) {
          acc[0][n] += a0.x * wv[n].x; acc[0][n] += a1.x * wv[n].y;
          acc[0][n] += a2.x * wv[n].z; acc[0][n] += a3.x * wv[n].w;
          acc[1][n] += a0.y * wv[n].x; acc[1][n] += a1.y * wv[n].y;
          acc[1][n] += a2.y * wv[n].z; acc[1][n] += a3.y * wv[n].w;
        }
      }
    }

    // write staged x regs into the next buffer (after compute so loads arrived)
    if (nxt >= 4 && nxt < NCHK) {
      float* dst = &HX[nxt & 1][0];
      const int bq = tid & 127;
      const int eg = tid >> 7;
      #pragma unroll
      for (int r = 0; r < 8; ++r) {
        const int el = eg * 32 + r * 4;
        dst[(el + 0) * Bn + bq] = xr[r].x;
        dst[(el + 1) * Bn + bq] = xr[r].y;
        dst[(el + 2) * Bn + bq] = xr[r].z;
        dst[(el + 3) * Bn + bq] = xr[r].w;
      }
    }
    __syncthreads();
  }

  // ---- reduce 8 wave-partials: P[wid][n][b], conflict-free b64 writes ----
  float* P = &HX[0][0];                              // 8*8*128 = 8192 floats
  #pragma unroll
  for (int n = 0; n < 8; ++n)
    *(float2*)&P[((wid * 8) + n) * Bn + lane * 2] = make_float2(acc[0][n], acc[1][n]);
  __syncthreads();
  {
    const int b  = tid & 127;
    const int ng = tid >> 7;                         // 0..3
    #pragma unroll
    for (int cg2 = 0; cg2 < 2; ++cg2)
      #pragma unroll
      for (int nn = 0; nn < 2; ++nn) {
        const int n = ng * 2 + nn;
        float v = 0.f;
        #pragma unroll
        for (int k2 = 0; k2 < 4; ++k2)
          v += P[((k2 * 2 + cg2) * 8 + n) * Bn + b];
        GL[b * 17 + cg2 * 8 + n] = v;
      }
  }
  __syncthreads();

  // ---- LSTM pointwise update: 512 items = 128 b x 4 hh ----
  {
    const int b  = tid & 127;
    const int hh = tid >> 7;
    const int hidx = hidx0 + hh;
    const float gi = GL[b * 17 + hh]      + bias[hidx];
    const float gf = GL[b * 17 + 4 + hh]  + bias[Hn + hidx];
    const float gc = GL[b * 17 + 8 + hh]  + bias[2 * Hn + hidx];
    const float go = GL[b * 17 + 12 + hh] + bias[3 * Hn + hidx];
    const float iv = 1.f / (1.f + expf(-gi));
    const float fv = 1.f / (1.f + expf(-gf));
    const float gv = tanhf(gc);
    const float ov = 1.f / (1.f + expf(-go));
    const float cold = cbuf[hidx * Bn + b];
    const float cnew = fv * cold + iv * gv;
    const float hold = hprev[hidx * Bn + b];
    const float hnew = ov * tanhf(cnew);
    const float m = masks[(size_t)b * Tn + t];
    hnext[hidx * Bn + b] = (m > 0.f) ? hnew : hold;
    cbuf[hidx * Bn + b]  = (m > 0.f) ? cnew : cold;
  }

  // ---- emission tail: blocks 0..63 compute E[tprev][tag][:] ----
  if (blk < 64 && s > 0) {
    __syncthreads();
    float* RS = &HX[0][0];                           // [16][128]
    const int dir_e = blk >> 5;
    const int tag   = blk & 31;
    const float* hsrc = ws + (dir_e ? OFF_HB : OFF_HF) + rbuf * (Hn * Bn);
    const int tprev = dir_e ? (Tn - s) : (s - 1);
    const float* wrow = Wout + (size_t)tag * (2 * Hn) + dir_e * Hn;  // uniform
    float* Edst = ws + (dir_e ? OFF_EB : OFF_EF);
    const int bq = tid & 31;
    const int kg = tid >> 5;                         // 16 groups x 32 k
    float4 a4 = make_float4(0.f, 0.f, 0.f, 0.f);
    #pragma unroll 4
    for (int kk = 0; kk < 32; ++kk) {
      const int k = kg * 32 + kk;
      const float w = wrow[k];
      const float4 h4 = *(const float4*)&hsrc[k * Bn + bq * 4];
      a4.x += h4.x * w; a4.y += h4.y * w; a4.z += h4.z * w; a4.w += h4.w * w;
    }
    *(float4*)&RS[kg * Bn + bq * 4] = a4;
    __syncthreads();
    if (tid < 128) {
      float v = 0.f;
      #pragma unroll
      for (int g = 0; g < 16; ++g) v += RS[g * Bn + tid];
      Edst[(size_t)tprev * (NTAGS * Bn) + tag * Bn + tid] = v;
    }
  }
}

__global__ __launch_bounds__(512) void emis_final_k(const float* __restrict__ Wout,
                                                    float* __restrict__ ws)
{
  __shared__ float RS[16 * Bn];
  const int tid = threadIdx.x;
  const int dir = blockIdx.x >> 5;
  const int tag = blockIdx.x & 31;
  // final states: h_f[T-1] and h_b[0] both written at s=511 (wbuf=1)
  const float* hsrc = ws + (dir ? OFF_HB : OFF_HF) + 1 * (Hn * Bn);
  const int tprev = dir ? 0 : (Tn - 1);
  const float* wrow = Wout + (size_t)tag * (2 * Hn) + dir * Hn;
  float* Edst = ws + (dir ? OFF_EB : OFF_EF);
  const int bq = tid & 31;
  const int kg = tid >> 5;
  float4 a4 = make_float4(0.f, 0.f, 0.f, 0.f);
  #pragma unroll 4
  for (int kk = 0; kk < 32; ++kk) {
    const int k = kg * 32 + kk;
    const float w = wrow[k];
    const float4 h4 = *(const float4*)&hsrc[k * Bn + bq * 4];
    a4.x += h4.x * w; a4.y += h4.y * w; a4.z += h4.z * w; a4.w += h4.w * w;
  }
  *(float4*)&RS[kg * Bn + bq * 4] = a4;
  __syncthreads();
  if (tid < 128) {
    float v = 0.f;
    #pragma unroll
    for (int g = 0; g < 16; ++g) v += RS[g * Bn + tid];
    Edst[(size_t)tprev * (NTAGS * Bn) + tag * Bn + tid] = v;
  }
}

__global__ __launch_bounds__(64) void viterbi_k(
    const float* __restrict__ Ef, const float* __restrict__ Eb,
    const float* __restrict__ bout, const float* __restrict__ trans,
    const float* __restrict__ masks, float* __restrict__ out)
{
  const int b = blockIdx.x;
  const int l = threadIdx.x;
  __shared__ float tr[32][32];
  __shared__ float al[32];
  __shared__ float msk[512];
  __shared__ unsigned char bp[512][32];
  __shared__ int tseq[512];

  for (int i = l; i < 1024; i += 64) tr[i >> 5][i & 31] = trans[i];
  for (int i = l; i < 512; i += 64) msk[i] = masks[(size_t)b * 512 + i];
  __syncthreads();

  const int j  = l & 31;
  const int hi = l >> 5;
  if (l < 32)
    al[j] = Ef[(size_t)j * Bn + b] + Eb[(size_t)j * Bn + b] + bout[j] + tr[30][j];
  __syncthreads();

  for (int t = 1; t < 512; ++t) {
    float pmax = -FLT_MAX; int pidx = 0;
    #pragma unroll
    for (int ii = 0; ii < 16; ++ii) {
      const int i = hi * 16 + ii;
      const float sc = al[i] + tr[i][j];
      if (sc > pmax) { pmax = sc; pidx = i; }   // strict > => first occurrence
    }
    const float omax = __shfl_down(pmax, 32);
    const int   oidx = __shfl_down(pidx, 32);
    if (l < 32) {
      if (omax > pmax) { pmax = omax; pidx = oidx; } // high half only on strict >
      bp[t][j] = (unsigned char)pidx;
      const float e = Ef[(size_t)t * (NTAGS * Bn) + j * Bn + b]
                    + Eb[(size_t)t * (NTAGS * Bn) + j * Bn + b] + bout[j];
      const float na = pmax + e;
      if (msk[t] > 0.f) al[j] = na;
    }
    __syncthreads();
  }

  float fv; int fidx;
  if (l < 32) { fv = al[l] + tr[l][31]; fidx = l; }
  else        { fv = -FLT_MAX; fidx = 1 << 30; }
  #pragma unroll
  for (int off = 16; off >= 1; off >>= 1) {
    const float v2 = __shfl_xor(fv, off);
    const int   i2 = __shfl_xor(fidx, off);
    if (v2 > fv || (v2 == fv && i2 < fidx)) { fv = v2; fidx = i2; }
  }
  if (l == 0) {
    out[b] = fv;
    int cur = fidx;
    tseq[511] = cur;
    for (int t = 511; t >= 1; --t) {
      const int prev = (msk[t] > 0.f) ? (int)bp[t][cur] : cur;
      tseq[t - 1] = prev;
      cur = prev;
    }
  }
  __syncthreads();
  for (int t = l; t < 512; t += 64) {
    const float tv = (msk[t] > 0.f) ? (float)tseq[t] : -1.0f;
    out[Bn + (size_t)b * 512 + t] = tv;
  }
}

extern "C" void kernel_launch(void* const* d_in, const int* in_sizes, int n_in,
                              void* d_out, int out_size, void* d_ws, size_t ws_size,
                              hipStream_t stream) {
  const float* X      = (const float*)d_in[0];
  const float* masks  = (const float*)d_in[1];
  const float* Wih_f  = (const float*)d_in[3];
  const float* Whh_f  = (const float*)d_in[4];
  const float* bf     = (const float*)d_in[5];
  const float* Wih_b  = (const float*)d_in[6];
  const float* Whh_b  = (const float*)d_in[7];
  const float* bb     = (const float*)d_in[8];
  const float* Wout   = (const float*)d_in[9];
  const float* bout   = (const float*)d_in[10];
  const float* trans  = (const float*)d_in[11];
  float* ws  = (float*)d_ws;
  float* out = (float*)d_out;

  // zero h/c state region (graph replays re-run this)
  hipMemsetAsync(d_ws, 0, (size_t)OFF_EF * sizeof(float), stream);

  for (int s = 0; s < Tn; ++s)
    lstm_step_k<<<256, 512, 0, stream>>>(X, masks, Wih_f, Whh_f, bf,
                                         Wih_b, Whh_b, bb, Wout, ws, s);
  emis_final_k<<<64, 512, 0, stream>>>(Wout, ws);
  viterbi_k<<<128, 64, 0, stream>>>(ws + OFF_EF, ws + OFF_EB, bout, trans, masks, out);
}

// Round 4
// 12234.666 us; speedup vs baseline: 2.6180x; 1.5105x over previous
//
#include <hip/hip_runtime.h>
#include <cfloat>
#include <cmath>

#define Bn 128
#define Tn 512
#define En 256
#define Hn 512
#define NTAGS 32
#define CHK 64                   // k-rows per staged chunk
#define NCHK 12                  // 8 h-chunks (512 k) + 4 x-chunks (256 k)

// ws float offsets (h stored transposed [k][b], unpadded: gll16 linear dest)
#define OFF_HF 0                          // [2][512][128]
#define OFF_HB 131072
#define OFF_CF 262144                     // [512][128]
#define OFF_CB 327680
#define OFF_EF 393216                     // [512][32][128]
#define OFF_EB 2490368
// end 4587520 floats = 17.5 MB

__device__ __forceinline__ void gll16(const float* g, float* l) {
  __builtin_amdgcn_global_load_lds(
      (const __attribute__((address_space(1))) void*)g,
      (__attribute__((address_space(3))) void*)l, 16, 0, 0);
}

__global__ __launch_bounds__(512, 2) void lstm_step_k(
    const float* __restrict__ X, const float* __restrict__ masks,
    const float* __restrict__ Wih_f, const float* __restrict__ Whh_f, const float* __restrict__ bias_f,
    const float* __restrict__ Wih_b, const float* __restrict__ Whh_b, const float* __restrict__ bias_b,
    const float* __restrict__ Wout, float* __restrict__ ws, int s)
{
  __shared__ __align__(16) float WT[768 * 16];     // 48 KB  W [k][c]
  __shared__ __align__(16) float HX[2][CHK * Bn];  // 64 KB  A chunks [k][b]
  __shared__ __align__(16) float GL[Bn * 17];      // 8.5 KB gates [b][c]
  __shared__ __align__(16) float WoL[512];         // 2 KB   Wout row (this block's tag)
  __shared__ __align__(16) float RS[16 * 32];      // 2 KB   emission partials

  const int tid  = threadIdx.x;
  const int blk  = blockIdx.x;
  const int lane = tid & 63;
  const int wid  = __builtin_amdgcn_readfirstlane(tid >> 6);  // 0..7 uniform
  const int cg   = wid & 1;    // col half: [cg*8, cg*8+8)
  const int kt   = wid >> 1;   // k quarter of chunk: [kt*16, kt*16+16)

  const int dir = blk >> 7;
  const int bbk = blk & 127;
  const int t = dir ? (Tn - 1 - s) : s;
  const float* Wih  = dir ? Wih_b  : Wih_f;
  const float* Whh  = dir ? Whh_b  : Whh_f;
  const float* bias = dir ? bias_b : bias_f;
  float* hbuf = ws + (dir ? OFF_HB : OFF_HF);
  float* cbuf = ws + (dir ? OFF_CB : OFF_CF);
  const int rbuf = (s + 1) & 1;
  const int wbuf = s & 1;
  const float* hprev = hbuf + rbuf * (Hn * Bn);
  float*       hnext = hbuf + wbuf * (Hn * Bn);
  const int hidx0 = bbk * 4;

  // emission role of this block: (dir, tag, 32-wide b slice)
  const int etag = bbk & 31;
  const int ebq  = bbk >> 5;

  // ---- prologue: issue chunk-0 staging, then stage W and WoL to LDS ----
  #pragma unroll
  for (int r = 0; r < 4; ++r) {
    const int item = r * 512 + tid;                // 2048 float4
    gll16(hprev + item * 4, &HX[0][item * 4]);
  }
  {
    const int lc  = tid & 15;
    const int q   = tid >> 4;                      // 0..31
    const int row = (lc >> 2) * Hn + hidx0 + (lc & 3);
    #pragma unroll
    for (int i = 0; i < 6; ++i) {
      const int k4 = q + i * 32;                   // 0..191
      const int k  = k4 * 4;
      float4 w4;
      if (k < Hn) w4 = *(const float4*)&Whh[(size_t)row * Hn + k];
      else        w4 = *(const float4*)&Wih[(size_t)row * En + (k - Hn)];
      WT[(k + 0) * 16 + lc] = w4.x; WT[(k + 1) * 16 + lc] = w4.y;
      WT[(k + 2) * 16 + lc] = w4.z; WT[(k + 3) * 16 + lc] = w4.w;
    }
  }
  if (tid < 128) {
    const float4 wo = *(const float4*)&Wout[(size_t)etag * (2 * Hn) + dir * Hn + tid * 4];
    WoL[tid * 4 + 0] = wo.x; WoL[tid * 4 + 1] = wo.y;
    WoL[tid * 4 + 2] = wo.z; WoL[tid * 4 + 3] = wo.w;
  }
  __syncthreads();

  float acc[2][8];
  #pragma unroll
  for (int m = 0; m < 2; ++m)
    #pragma unroll
    for (int n = 0; n < 8; ++n) acc[m][n] = 0.f;
  float eacc = 0.f;
  float4 xr[4];

  // ---- main loop: 12 chunks of 64 k ----
  #pragma unroll 1
  for (int c = 0; c < NCHK; ++c) {
    const int nxt = c + 1;
    if (nxt < 8) {
      const float* src = hprev + nxt * (CHK * Bn);
      float* dst = &HX[nxt & 1][0];
      #pragma unroll
      for (int r = 0; r < 4; ++r) {
        const int item = r * 512 + tid;
        gll16(src + item * 4, dst + item * 4);
      }
    } else if (nxt < NCHK) {
      const int e0 = (nxt - 8) * 64;
      const int bq = tid & 127;
      const int eg = tid >> 7;                     // 0..3
      #pragma unroll
      for (int r = 0; r < 4; ++r)
        xr[r] = *(const float4*)&X[(size_t)bq * (Tn * En) + (size_t)t * En + e0 + eg * 16 + r * 4];
    }

    // ---- compute chunk c: A from LDS b64, W from LDS uniform b128 broadcast ----
    {
      const float* HXc = &HX[c & 1][0];
      const int kgb = c * 64 + kt * 16;
      #pragma unroll
      for (int kk = 0; kk < 16; ++kk) {
        const int kl = kt * 16 + kk;
        const float2 av = *(const float2*)&HXc[kl * Bn + lane * 2];
        const float4 wa = *(const float4*)&WT[(kgb + kk) * 16 + cg * 8];
        const float4 wb = *(const float4*)&WT[(kgb + kk) * 16 + cg * 8 + 4];
        acc[0][0] += av.x * wa.x; acc[0][1] += av.x * wa.y;
        acc[0][2] += av.x * wa.z; acc[0][3] += av.x * wa.w;
        acc[0][4] += av.x * wb.x; acc[0][5] += av.x * wb.y;
        acc[0][6] += av.x * wb.z; acc[0][7] += av.x * wb.w;
        acc[1][0] += av.y * wa.x; acc[1][1] += av.y * wa.y;
        acc[1][2] += av.y * wa.z; acc[1][3] += av.y * wa.w;
        acc[1][4] += av.y * wb.x; acc[1][5] += av.y * wb.y;
        acc[1][6] += av.y * wb.z; acc[1][7] += av.y * wb.w;
      }
      // emission partial from the same LDS panel (h-chunks only)
      if (c < 8) {
        const int be  = tid & 31;
        const int kq  = tid >> 5;                  // 0..15
        const int eb0 = ebq * 32 + be;
        #pragma unroll
        for (int j = 0; j < 4; ++j)
          eacc += HXc[(kq * 4 + j) * Bn + eb0] * WoL[c * 64 + kq * 4 + j];
      }
    }

    // write staged x regs into the next buffer (its prior readers synced 1 barrier ago)
    if (nxt >= 8 && nxt < NCHK) {
      float* dst = &HX[nxt & 1][0];
      const int bq = tid & 127;
      const int eg = tid >> 7;
      #pragma unroll
      for (int r = 0; r < 4; ++r) {
        const int el = eg * 16 + r * 4;
        dst[(el + 0) * Bn + bq] = xr[r].x;
        dst[(el + 1) * Bn + bq] = xr[r].y;
        dst[(el + 2) * Bn + bq] = xr[r].z;
        dst[(el + 3) * Bn + bq] = xr[r].w;
      }
    }
    __syncthreads();
  }

  // ---- stash emission partial, reduce GEMM k-split via LDS ----
  RS[(tid >> 5) * 32 + (tid & 31)] = eacc;
  float* P = &HX[0][0];                            // 8192 floats
  #pragma unroll
  for (int n = 0; n < 8; ++n)
    *(float2*)&P[((wid * 8) + n) * Bn + lane * 2] = make_float2(acc[0][n], acc[1][n]);
  __syncthreads();
  {
    const int b  = tid & 127;
    const int ng = tid >> 7;                       // 0..3
    #pragma unroll
    for (int cg2 = 0; cg2 < 2; ++cg2)
      #pragma unroll
      for (int nn = 0; nn < 2; ++nn) {
        const int n = ng * 2 + nn;
        float v = 0.f;
        #pragma unroll
        for (int k2 = 0; k2 < 4; ++k2)
          v += P[((k2 * 2 + cg2) * 8 + n) * Bn + b];
        GL[b * 17 + cg2 * 8 + n] = v;
      }
  }
  __syncthreads();

  // ---- LSTM pointwise update ----
  {
    const int b  = tid & 127;
    const int hh = tid >> 7;
    const int hidx = hidx0 + hh;
    const float gi = GL[b * 17 + hh]      + bias[hidx];
    const float gf = GL[b * 17 + 4 + hh]  + bias[Hn + hidx];
    const float gc = GL[b * 17 + 8 + hh]  + bias[2 * Hn + hidx];
    const float go = GL[b * 17 + 12 + hh] + bias[3 * Hn + hidx];
    const float iv = 1.f / (1.f + expf(-gi));
    const float fv = 1.f / (1.f + expf(-gf));
    const float gv = tanhf(gc);
    const float ov = 1.f / (1.f + expf(-go));
    const float cold = cbuf[hidx * Bn + b];
    const float cnew = fv * cold + iv * gv;
    const float hold = hprev[hidx * Bn + b];
    const float hnew = ov * tanhf(cnew);
    const float m = masks[(size_t)b * Tn + t];
    hnext[hidx * Bn + b] = (m > 0.f) ? hnew : hold;
    cbuf[hidx * Bn + b]  = (m > 0.f) ? cnew : cold;
  }

  // ---- emission finish: E_dir[tprev][etag][ebq slice] ----
  if (tid < 32 && s > 0) {
    const int tprev = dir ? (Tn - s) : (s - 1);
    float* Edst = ws + (dir ? OFF_EB : OFF_EF);
    float v = 0.f;
    #pragma unroll
    for (int g = 0; g < 16; ++g) v += RS[g * 32 + tid];
    Edst[(size_t)tprev * (NTAGS * Bn) + etag * Bn + ebq * 32 + tid] = v;
  }
}

__global__ __launch_bounds__(512) void emis_final_k(const float* __restrict__ Wout,
                                                    float* __restrict__ ws)
{
  __shared__ float RSf[16 * Bn];
  const int tid = threadIdx.x;
  const int dir = blockIdx.x >> 5;
  const int tag = blockIdx.x & 31;
  // final states: h_f[T-1] and h_b[0] both written at s=511 (wbuf=1)
  const float* hsrc = ws + (dir ? OFF_HB : OFF_HF) + 1 * (Hn * Bn);
  const int tprev = dir ? 0 : (Tn - 1);
  const float* wrow = Wout + (size_t)tag * (2 * Hn) + dir * Hn;
  float* Edst = ws + (dir ? OFF_EB : OFF_EF);
  const int bq = tid & 31;
  const int kg = tid >> 5;
  float4 a4 = make_float4(0.f, 0.f, 0.f, 0.f);
  #pragma unroll 4
  for (int kk = 0; kk < 32; ++kk) {
    const int k = kg * 32 + kk;
    const float w = wrow[k];
    const float4 h4 = *(const float4*)&hsrc[k * Bn + bq * 4];
    a4.x += h4.x * w; a4.y += h4.y * w; a4.z += h4.z * w; a4.w += h4.w * w;
  }
  *(float4*)&RSf[kg * Bn + bq * 4] = a4;
  __syncthreads();
  if (tid < 128) {
    float v = 0.f;
    #pragma unroll
    for (int g = 0; g < 16; ++g) v += RSf[g * Bn + tid];
    Edst[(size_t)tprev * (NTAGS * Bn) + tag * Bn + tid] = v;
  }
}

__global__ __launch_bounds__(64) void viterbi_k(
    const float* __restrict__ Ef, const float* __restrict__ Eb,
    const float* __restrict__ bout, const float* __restrict__ trans,
    const float* __restrict__ masks, float* __restrict__ out)
{
  const int b = blockIdx.x;
  const int l = threadIdx.x;
  __shared__ float tr[32][32];
  __shared__ float al[32];
  __shared__ float msk[512];
  __shared__ unsigned char bp[512][32];
  __shared__ int tseq[512];

  for (int i = l; i < 1024; i += 64) tr[i >> 5][i & 31] = trans[i];
  for (int i = l; i < 512; i += 64) msk[i] = masks[(size_t)b * 512 + i];
  __syncthreads();

  const int j  = l & 31;
  const int hi = l >> 5;
  if (l < 32)
    al[j] = Ef[(size_t)j * Bn + b] + Eb[(size_t)j * Bn + b] + bout[j] + tr[30][j];
  __syncthreads();

  for (int t = 1; t < 512; ++t) {
    float pmax = -FLT_MAX; int pidx = 0;
    #pragma unroll
    for (int ii = 0; ii < 16; ++ii) {
      const int i = hi * 16 + ii;
      const float sc = al[i] + tr[i][j];
      if (sc > pmax) { pmax = sc; pidx = i; }   // strict > => first occurrence
    }
    const float omax = __shfl_down(pmax, 32);
    const int   oidx = __shfl_down(pidx, 32);
    if (l < 32) {
      if (omax > pmax) { pmax = omax; pidx = oidx; } // high half only on strict >
      bp[t][j] = (unsigned char)pidx;
      const float e = Ef[(size_t)t * (NTAGS * Bn) + j * Bn + b]
                    + Eb[(size_t)t * (NTAGS * Bn) + j * Bn + b] + bout[j];
      const float na = pmax + e;
      if (msk[t] > 0.f) al[j] = na;
    }
    __syncthreads();
  }

  float fv; int fidx;
  if (l < 32) { fv = al[l] + tr[l][31]; fidx = l; }
  else        { fv = -FLT_MAX; fidx = 1 << 30; }
  #pragma unroll
  for (int off = 16; off >= 1; off >>= 1) {
    const float v2 = __shfl_xor(fv, off);
    const int   i2 = __shfl_xor(fidx, off);
    if (v2 > fv || (v2 == fv && i2 < fidx)) { fv = v2; fidx = i2; }
  }
  if (l == 0) {
    out[b] = fv;
    int cur = fidx;
    tseq[511] = cur;
    for (int t = 511; t >= 1; --t) {
      const int prev = (msk[t] > 0.f) ? (int)bp[t][cur] : cur;
      tseq[t - 1] = prev;
      cur = prev;
    }
  }
  __syncthreads();
  for (int t = l; t < 512; t += 64) {
    const float tv = (msk[t] > 0.f) ? (float)tseq[t] : -1.0f;
    out[Bn + (size_t)b * 512 + t] = tv;
  }
}

extern "C" void kernel_launch(void* const* d_in, const int* in_sizes, int n_in,
                              void* d_out, int out_size, void* d_ws, size_t ws_size,
                              hipStream_t stream) {
  const float* X      = (const float*)d_in[0];
  const float* masks  = (const float*)d_in[1];
  const float* Wih_f  = (const float*)d_in[3];
  const float* Whh_f  = (const float*)d_in[4];
  const float* bf     = (const float*)d_in[5];
  const float* Wih_b  = (const float*)d_in[6];
  const float* Whh_b  = (const float*)d_in[7];
  const float* bb     = (const float*)d_in[8];
  const float* Wout   = (const float*)d_in[9];
  const float* bout   = (const float*)d_in[10];
  const float* trans  = (const float*)d_in[11];
  float* ws  = (float*)d_ws;
  float* out = (float*)d_out;

  // zero h/c state region (graph replays re-run this)
  hipMemsetAsync(d_ws, 0, (size_t)OFF_EF * sizeof(float), stream);

  for (int s = 0; s < Tn; ++s)
    lstm_step_k<<<256, 512, 0, stream>>>(X, masks, Wih_f, Whh_f, bf,
                                         Wih_b, Whh_b, bb, Wout, ws, s);
  emis_final_k<<<64, 512, 0, stream>>>(Wout, ws);
  viterbi_k<<<128, 64, 0, stream>>>(ws + OFF_EF, ws + OFF_EB, bout, trans, masks, out);
}

// Round 5
// 11368.233 us; speedup vs baseline: 2.8175x; 1.0762x over previous
//
#include <hip/hip_runtime.h>
#include <cfloat>
#include <cmath>

#define Bn 128
#define Tn 512
#define En 256
#define Hn 512
#define NTAGS 32
#define CHK 64                   // k-rows per staged chunk
#define NCHK 12                  // 8 h-chunks (512 k) + 4 x-chunks (256 k)
#define LDW 132                  // padded LDS row stride (132 % 32 != 0 -> bank spread)
#define WPAD 20                  // padded W row stride

// ws float offsets (h stored [k][b] dense)
#define OFF_HF 0                          // [2][512][128]
#define OFF_HB 131072
#define OFF_CF 262144                     // [512][128]
#define OFF_CB 327680
#define OFF_EF 393216                     // [512][32][128]
#define OFF_EB 2490368
// end 4587520 floats = 17.5 MB

__global__ __launch_bounds__(512, 2) void lstm_step_k(
    const float* __restrict__ X, const float* __restrict__ masks,
    const float* __restrict__ Wih_f, const float* __restrict__ Whh_f, const float* __restrict__ bias_f,
    const float* __restrict__ Wih_b, const float* __restrict__ Whh_b, const float* __restrict__ bias_b,
    const float* __restrict__ Wout, float* __restrict__ ws, int s)
{
  __shared__ __align__(16) float WT[768 * WPAD];    // 61.4 KB  W [k][c] padded
  __shared__ __align__(16) float HX[2][CHK * LDW];  // 67.6 KB  A chunks [k][b] padded
  __shared__ __align__(16) float GL[Bn * 17];       // 8.7 KB   gates [b][c]
  __shared__ __align__(16) float WoL[512];          // 2 KB     Wout row (block's tag)
  __shared__ __align__(16) float RS[16 * 32];       // 2 KB     emission partials

  const int tid   = threadIdx.x;
  const int blk   = blockIdx.x;
  const int lane  = tid & 63;
  const int wid   = __builtin_amdgcn_readfirstlane(tid >> 6);  // 0..7 uniform
  const int cg    = wid & 1;    // c half: cols [cg*8, cg*8+8)
  const int kt    = wid >> 1;   // k quarter of chunk: [kt*16, +16)
  const int bg    = lane & 31;  // b quad: [bg*4, +4)
  const int khalf = lane >> 5;  // k parity within pair

  const int dir = blk >> 7;
  const int bbk = blk & 127;
  const int t = dir ? (Tn - 1 - s) : s;
  const float* Wih  = dir ? Wih_b  : Wih_f;
  const float* Whh  = dir ? Whh_b  : Whh_f;
  const float* bias = dir ? bias_b : bias_f;
  float* hbuf = ws + (dir ? OFF_HB : OFF_HF);
  float* cbuf = ws + (dir ? OFF_CB : OFF_CF);
  const int rbuf = (s + 1) & 1;
  const int wbuf = s & 1;
  const float* hprev = hbuf + rbuf * (Hn * Bn);
  float*       hnext = hbuf + wbuf * (Hn * Bn);
  const int hidx0 = bbk * 4;

  // emission role: (dir, tag, 32-wide b slice)
  const int etag = bbk & 31;
  const int ebq  = bbk >> 5;

  // ---- prologue: stage W (once), WoL, and chunk 0 ----
  {
    const int lc = tid & 15;
    const int kw = tid >> 4;                       // 0..31
    const int row = (lc >> 2) * Hn + hidx0 + (lc & 3);
    #pragma unroll
    for (int i = 0; i < 6; ++i) {
      const int k = (kw + i * 32) * 4;             // 0..764
      float4 w4;
      if (k < Hn) w4 = *(const float4*)&Whh[(size_t)row * Hn + k];
      else        w4 = *(const float4*)&Wih[(size_t)row * En + (k - Hn)];
      WT[(k + 0) * WPAD + lc] = w4.x; WT[(k + 1) * WPAD + lc] = w4.y;
      WT[(k + 2) * WPAD + lc] = w4.z; WT[(k + 3) * WPAD + lc] = w4.w;
    }
  }
  if (tid < 128) {
    const float4 wo = *(const float4*)&Wout[(size_t)etag * (2 * Hn) + dir * Hn + tid * 4];
    *(float4*)&WoL[tid * 4] = wo;
  }
  {
    #pragma unroll
    for (int r = 0; r < 4; ++r) {
      const int item = r * 512 + tid;              // 2048 float4 = 64x128
      const float4 v = *(const float4*)&hprev[item * 4];
      const int k = item >> 5;
      const int g = item & 31;
      *(float4*)&HX[0][k * LDW + g * 4] = v;
    }
  }
  __syncthreads();

  float acc[4][8];
  #pragma unroll
  for (int m = 0; m < 4; ++m)
    #pragma unroll
    for (int n = 0; n < 8; ++n) acc[m][n] = 0.f;
  float eacc = 0.f;

  const int xbq = tid & 127;                       // for x staging
  const int xeg = tid >> 7;                        // 0..3

  // ---- main loop: 12 chunks of 64 k ----
  #pragma unroll 1
  for (int c = 0; c < NCHK; ++c) {
    const int nxt = c + 1;
    float4 st[4];
    if (nxt < 8) {
      const float* src = hprev + nxt * (CHK * Bn);
      #pragma unroll
      for (int r = 0; r < 4; ++r)
        st[r] = *(const float4*)&src[(r * 512 + tid) * 4];
    } else if (nxt < NCHK) {
      const int e0 = (nxt - 8) * CHK;
      #pragma unroll
      for (int r = 0; r < 4; ++r)
        st[r] = *(const float4*)&X[(size_t)xbq * (Tn * En) + (size_t)t * En + e0 + xeg * 16 + r * 4];
    }

    // ---- compute chunk c ----
    {
      const float* HXc = &HX[c & 1][0];
      #pragma unroll
      for (int j = 0; j < 8; ++j) {
        const int l = kt * 16 + j * 2 + khalf;     // local k
        const float4 av = *(const float4*)&HXc[l * LDW + bg * 4];
        const float4 wa = *(const float4*)&WT[(c * 64 + l) * WPAD + cg * 8];
        const float4 wb = *(const float4*)&WT[(c * 64 + l) * WPAD + cg * 8 + 4];
        const float avf[4] = {av.x, av.y, av.z, av.w};
        const float wvf[8] = {wa.x, wa.y, wa.z, wa.w, wb.x, wb.y, wb.z, wb.w};
        #pragma unroll
        for (int m = 0; m < 4; ++m)
          #pragma unroll
          for (int n = 0; n < 8; ++n)
            acc[m][n] += avf[m] * wvf[n];
      }
      // emission partial from same panel (h-chunks only)
      if (c < 8) {
        const int be = tid & 31;
        const int kq = tid >> 5;                   // 0..15
        #pragma unroll
        for (int j = 0; j < 4; ++j)
          eacc += HXc[(kq * 4 + j) * LDW + ebq * 32 + be] * WoL[c * 64 + kq * 4 + j];
      }
    }

    // ---- write staged regs into next buffer ----
    if (nxt < 8) {
      float* dst = &HX[nxt & 1][0];
      #pragma unroll
      for (int r = 0; r < 4; ++r) {
        const int item = r * 512 + tid;
        const int k = item >> 5;
        const int g = item & 31;
        *(float4*)&dst[k * LDW + g * 4] = st[r];
      }
    } else if (nxt < NCHK) {
      float* dst = &HX[nxt & 1][0];
      #pragma unroll
      for (int r = 0; r < 4; ++r) {
        const int el = xeg * 16 + r * 4;
        dst[(el + 0) * LDW + xbq] = st[r].x;
        dst[(el + 1) * LDW + xbq] = st[r].y;
        dst[(el + 2) * LDW + xbq] = st[r].z;
        dst[(el + 3) * LDW + xbq] = st[r].w;
      }
    }
    __syncthreads();
  }

  // ---- k-split reduction: P[ks=kt*2+khalf][c16][b128] overlaid on HX ----
  float* P = &HX[0][0];                            // 16384 floats
  const int ks = kt * 2 + khalf;
  #pragma unroll
  for (int n = 0; n < 8; ++n)
    *(float4*)&P[ks * 2048 + (cg * 8 + n) * 128 + bg * 4] =
        make_float4(acc[0][n], acc[1][n], acc[2][n], acc[3][n]);
  RS[(tid >> 5) * 32 + (tid & 31)] = eacc;
  __syncthreads();
  {
    const int b  = tid & 127;
    const int cq = tid >> 7;                       // 0..3
    float g4[4] = {0.f, 0.f, 0.f, 0.f};
    #pragma unroll
    for (int k2 = 0; k2 < 8; ++k2)
      #pragma unroll
      for (int ci = 0; ci < 4; ++ci)
        g4[ci] += P[k2 * 2048 + (cq * 4 + ci) * 128 + b];
    #pragma unroll
    for (int ci = 0; ci < 4; ++ci)
      GL[b * 17 + cq * 4 + ci] = g4[ci];
  }
  __syncthreads();

  // ---- LSTM pointwise update ----
  {
    const int b  = tid & 127;
    const int hh = tid >> 7;
    const int hidx = hidx0 + hh;
    const float gi = GL[b * 17 + hh]      + bias[hidx];
    const float gf = GL[b * 17 + 4 + hh]  + bias[Hn + hidx];
    const float gc = GL[b * 17 + 8 + hh]  + bias[2 * Hn + hidx];
    const float go = GL[b * 17 + 12 + hh] + bias[3 * Hn + hidx];
    const float iv = 1.f / (1.f + expf(-gi));
    const float fv = 1.f / (1.f + expf(-gf));
    const float gv = tanhf(gc);
    const float ov = 1.f / (1.f + expf(-go));
    const float cold = cbuf[hidx * Bn + b];
    const float cnew = fv * cold + iv * gv;
    const float hold = hprev[hidx * Bn + b];
    const float hnew = ov * tanhf(cnew);
    const float m = masks[(size_t)b * Tn + t];
    hnext[hidx * Bn + b] = (m > 0.f) ? hnew : hold;
    cbuf[hidx * Bn + b]  = (m > 0.f) ? cnew : cold;
  }

  // ---- emission finish: E_dir[tprev][etag][ebq slice] ----
  if (tid < 32 && s > 0) {
    const int tprev = dir ? (Tn - s) : (s - 1);
    float* Edst = ws + (dir ? OFF_EB : OFF_EF);
    float v = 0.f;
    #pragma unroll
    for (int g = 0; g < 16; ++g) v += RS[g * 32 + tid];
    Edst[(size_t)tprev * (NTAGS * Bn) + etag * Bn + ebq * 32 + tid] = v;
  }
}

__global__ __launch_bounds__(512) void emis_final_k(const float* __restrict__ Wout,
                                                    float* __restrict__ ws)
{
  __shared__ float RSf[16 * Bn];
  const int tid = threadIdx.x;
  const int dir = blockIdx.x >> 5;
  const int tag = blockIdx.x & 31;
  // final states: h_f[T-1] and h_b[0] both written at s=511 (wbuf=1)
  const float* hsrc = ws + (dir ? OFF_HB : OFF_HF) + 1 * (Hn * Bn);
  const int tprev = dir ? 0 : (Tn - 1);
  const float* wrow = Wout + (size_t)tag * (2 * Hn) + dir * Hn;
  float* Edst = ws + (dir ? OFF_EB : OFF_EF);
  const int bq = tid & 31;
  const int kg = tid >> 5;
  float4 a4 = make_float4(0.f, 0.f, 0.f, 0.f);
  #pragma unroll 4
  for (int kk = 0; kk < 32; ++kk) {
    const int k = kg * 32 + kk;
    const float w = wrow[k];
    const float4 h4 = *(const float4*)&hsrc[k * Bn + bq * 4];
    a4.x += h4.x * w; a4.y += h4.y * w; a4.z += h4.z * w; a4.w += h4.w * w;
  }
  *(float4*)&RSf[kg * Bn + bq * 4] = a4;
  __syncthreads();
  if (tid < 128) {
    float v = 0.f;
    #pragma unroll
    for (int g = 0; g < 16; ++g) v += RSf[g * Bn + tid];
    Edst[(size_t)tprev * (NTAGS * Bn) + tag * Bn + tid] = v;
  }
}

__global__ __launch_bounds__(64) void viterbi_k(
    const float* __restrict__ Ef, const float* __restrict__ Eb,
    const float* __restrict__ bout, const float* __restrict__ trans,
    const float* __restrict__ masks, float* __restrict__ out)
{
  const int b = blockIdx.x;
  const int l = threadIdx.x;
  __shared__ float tr[32][32];
  __shared__ float al[32];
  __shared__ float msk[512];
  __shared__ unsigned char bp[512][32];
  __shared__ int tseq[512];

  for (int i = l; i < 1024; i += 64) tr[i >> 5][i & 31] = trans[i];
  for (int i = l; i < 512; i += 64) msk[i] = masks[(size_t)b * 512 + i];
  __syncthreads();

  const int j  = l & 31;
  const int hi = l >> 5;
  if (l < 32)
    al[j] = Ef[(size_t)j * Bn + b] + Eb[(size_t)j * Bn + b] + bout[j] + tr[30][j];
  __syncthreads();

  for (int t = 1; t < 512; ++t) {
    float pmax = -FLT_MAX; int pidx = 0;
    #pragma unroll
    for (int ii = 0; ii < 16; ++ii) {
      const int i = hi * 16 + ii;
      const float sc = al[i] + tr[i][j];
      if (sc > pmax) { pmax = sc; pidx = i; }   // strict > => first occurrence
    }
    const float omax = __shfl_down(pmax, 32);
    const int   oidx = __shfl_down(pidx, 32);
    if (l < 32) {
      if (omax > pmax) { pmax = omax; pidx = oidx; } // high half only on strict >
      bp[t][j] = (unsigned char)pidx;
      const float e = Ef[(size_t)t * (NTAGS * Bn) + j * Bn + b]
                    + Eb[(size_t)t * (NTAGS * Bn) + j * Bn + b] + bout[j];
      const float na = pmax + e;
      if (msk[t] > 0.f) al[j] = na;
    }
    __syncthreads();
  }

  float fv; int fidx;
  if (l < 32) { fv = al[l] + tr[l][31]; fidx = l; }
  else        { fv = -FLT_MAX; fidx = 1 << 30; }
  #pragma unroll
  for (int off = 16; off >= 1; off >>= 1) {
    const float v2 = __shfl_xor(fv, off);
    const int   i2 = __shfl_xor(fidx, off);
    if (v2 > fv || (v2 == fv && i2 < fidx)) { fv = v2; fidx = i2; }
  }
  if (l == 0) {
    out[b] = fv;
    int cur = fidx;
    tseq[511] = cur;
    for (int t = 511; t >= 1; --t) {
      const int prev = (msk[t] > 0.f) ? (int)bp[t][cur] : cur;
      tseq[t - 1] = prev;
      cur = prev;
    }
  }
  __syncthreads();
  for (int t = l; t < 512; t += 64) {
    const float tv = (msk[t] > 0.f) ? (float)tseq[t] : -1.0f;
    out[Bn + (size_t)b * 512 + t] = tv;
  }
}

extern "C" void kernel_launch(void* const* d_in, const int* in_sizes, int n_in,
                              void* d_out, int out_size, void* d_ws, size_t ws_size,
                              hipStream_t stream) {
  const float* X      = (const float*)d_in[0];
  const float* masks  = (const float*)d_in[1];
  const float* Wih_f  = (const float*)d_in[3];
  const float* Whh_f  = (const float*)d_in[4];
  const float* bf     = (const float*)d_in[5];
  const float* Wih_b  = (const float*)d_in[6];
  const float* Whh_b  = (const float*)d_in[7];
  const float* bb     = (const float*)d_in[8];
  const float* Wout   = (const float*)d_in[9];
  const float* bout   = (const float*)d_in[10];
  const float* trans  = (const float*)d_in[11];
  float* ws  = (float*)d_ws;
  float* out = (float*)d_out;

  // zero h/c state region (graph replays re-run this)
  hipMemsetAsync(d_ws, 0, (size_t)OFF_EF * sizeof(float), stream);

  for (int s = 0; s < Tn; ++s)
    lstm_step_k<<<256, 512, 0, stream>>>(X, masks, Wih_f, Whh_f, bf,
                                         Wih_b, Whh_b, bb, Wout, ws, s);
  emis_final_k<<<64, 512, 0, stream>>>(Wout, ws);
  viterbi_k<<<128, 64, 0, stream>>>(ws + OFF_EF, ws + OFF_EB, bout, trans, masks, out);
}